// Round 2
// baseline (9741.435 us; speedup 1.0000x reference)
//
#include <hip/hip_runtime.h>

typedef unsigned short u16;
using short8  = __attribute__((ext_vector_type(8))) short;
using floatx4 = __attribute__((ext_vector_type(4))) float;

// window one-sided sizes per layer (WINDOWS/2)
static const int g_halves[12] = {16,16,32,32,64,64,128,128,256,256,256,256};

__device__ __forceinline__ float bf2f(u16 u) {
  union { unsigned int i; float f; } x; x.i = ((unsigned int)u) << 16; return x.f;
}
__device__ __forceinline__ u16 f2bf(float f) {
  union { float f; unsigned int i; } x; x.f = f;
  unsigned int r = x.i + 0x7FFFu + ((x.i >> 16) & 1u);
  return (u16)(r >> 16);
}

// async 16B/lane global->LDS; dest is wave-uniform base, lane l lands at base + l*16
__device__ __forceinline__ void gld_lds16(const u16* g, u16* l) {
  __builtin_amdgcn_global_load_lds(
      (const __attribute__((address_space(1))) unsigned int*)g,
      (__attribute__((address_space(3))) unsigned int*)l, 16, 0, 0);
}

// ---------------------------------------------------------------------------
// fused transpose + f32->bf16 convert: in f32 [z][R][C] -> out bf16 [z][C][R]
// ---------------------------------------------------------------------------
__global__ __launch_bounds__(256) void transpose_cvt(
    const float* __restrict__ in, u16* __restrict__ out, int R, int C)
{
  __shared__ u16 t[32][33];
  const int tx = threadIdx.x & 31, ty = threadIdx.x >> 5; // 32 x 8
  const size_t base = (size_t)blockIdx.z * R * C;
  const int r0 = blockIdx.y * 32, c0 = blockIdx.x * 32;
#pragma unroll
  for (int j = 0; j < 32; j += 8)
    t[ty + j][tx] = f2bf(in[base + (size_t)(r0 + ty + j) * C + (c0 + tx)]);
  __syncthreads();
#pragma unroll
  for (int j = 0; j < 32; j += 8)
    out[base + (size_t)(c0 + ty + j) * R + (r0 + tx)] = t[tx][ty + j];
}

// ---------------------------------------------------------------------------
// GEMM: C[M,N] = A[M,K](bf16) @ B[K,N] given as Bt[N,K](bf16), + bias(f32)
// EPI 0: outF = acc+bias (f32)
// EPI 1: outF = acc+bias+res (f32)
// EPI 2: outB = bf16(gelu_exact(acc+bias))
// M%128==0, N%128==0, K%32==0
// ---------------------------------------------------------------------------
template<int EPI>
__global__ __launch_bounds__(256) void gemm_bt(
    const u16* __restrict__ A, const u16* __restrict__ Bt, const float* __restrict__ bias,
    const float* __restrict__ res, float* __restrict__ outF, u16* __restrict__ outB,
    int M, int N, int K)
{
  __shared__ __align__(16) u16 lsA[128 * 32];
  __shared__ __align__(16) u16 lsB[128 * 32];
  const int tid  = threadIdx.x;
  const int wave = tid >> 6, lane = tid & 63;
  const int quad = lane >> 4, l16 = lane & 15;
  const int m0 = blockIdx.y * 128, n0 = blockIdx.x * 128;
  const int wm = (wave >> 1) * 64, wn = (wave & 1) * 64;
  const int srow = lane >> 2;          // row within 16-row chunk
  const int skof = (lane & 3) * 8;     // bf16 offset along k

  floatx4 acc[4][4] = {};

  for (int k0 = 0; k0 < K; k0 += 32) {
    __syncthreads();
    // stage A-tile [128x32] and Bt-tile [128x32]; 16 chunks of 1KB, 4/wave
#pragma unroll
    for (int c = wave; c < 16; c += 4) {
      if (c < 8)
        gld_lds16(A  + (size_t)(m0 + c * 16 + srow) * K + k0 + skof, lsA + c * 512);
      else
        gld_lds16(Bt + (size_t)(n0 + (c - 8) * 16 + srow) * K + k0 + skof, lsB + (c - 8) * 512);
    }
    __syncthreads();
    short8 af[4], bfr[4];
#pragma unroll
    for (int i = 0; i < 4; ++i)
      af[i]  = *(const short8*)(lsA + (wm + i * 16 + l16) * 32 + quad * 8);
#pragma unroll
    for (int j = 0; j < 4; ++j)
      bfr[j] = *(const short8*)(lsB + (wn + j * 16 + l16) * 32 + quad * 8);
#pragma unroll
    for (int i = 0; i < 4; ++i)
#pragma unroll
      for (int j = 0; j < 4; ++j)
        acc[i][j] = __builtin_amdgcn_mfma_f32_16x16x32_bf16(af[i], bfr[j], acc[i][j], 0, 0, 0);
  }

#pragma unroll
  for (int i = 0; i < 4; ++i)
#pragma unroll
    for (int j = 0; j < 4; ++j) {
      const int col = n0 + wn + j * 16 + l16;
      const float bvl = bias[col];
#pragma unroll
      for (int r = 0; r < 4; ++r) {
        const int row = m0 + wm + i * 16 + quad * 4 + r;
        const size_t idx = (size_t)row * N + col;
        float v = acc[i][j][r] + bvl;
        if (EPI == 1) v += res[idx];
        if (EPI == 2) {
          v = 0.5f * v * (1.0f + erff(v * 0.70710678118654752f));
          outB[idx] = f2bf(v);
        } else {
          outF[idx] = v;
        }
      }
    }
}

// ---------------------------------------------------------------------------
// Sliding-window attention, fp32 VALU. grid (S/16, H, B), 256 thr.
// q,k,v: [B,S,768] f32 (col = h*64+d). ab out: [B,S,768] bf16.
// Band: keys in [t-half, t+half] clipped to [0,S). score = 0.125*q.k + key_add
// ---------------------------------------------------------------------------
__global__ __launch_bounds__(256) void attn_kernel(
    const float* __restrict__ q, const float* __restrict__ k, const float* __restrict__ v,
    const float* __restrict__ mask, u16* __restrict__ ab, int halfw)
{
  const int b = blockIdx.z, h = blockIdx.y, qt = blockIdx.x;
  const int wave = threadIdx.x >> 6, lane = threadIdx.x & 63;
  __shared__ float qs[16][64];
  __shared__ float ps[4][516];

  const size_t baseQ = ((size_t)b * 2048 + qt * 16) * 768 + h * 64;
  for (int i = threadIdx.x; i < 1024; i += 256)
    qs[i >> 6][i & 63] = q[baseQ + (size_t)(i >> 6) * 768 + (i & 63)];
  __syncthreads();

  for (int iq = 0; iq < 4; ++iq) {
    const int t  = qt * 16 + wave * 4 + iq;
    const int lo = (t - halfw > 0) ? (t - halfw) : 0;
    const int hi = (t + halfw < 2047) ? (t + halfw) : 2047;
    const int nk = hi - lo + 1;
    const float* qr = qs[wave * 4 + iq];

    // pass 1: scores
    float lmax = -3.0e38f;
    for (int j = lane; j < nk; j += 64) {
      const float* kr = k + ((size_t)b * 2048 + lo + j) * 768 + h * 64;
      float s = 0.f;
#pragma unroll
      for (int d = 0; d < 64; d += 4) {
        const float4 kv = *(const float4*)(kr + d);
        s += qr[d] * kv.x + qr[d + 1] * kv.y + qr[d + 2] * kv.z + qr[d + 3] * kv.w;
      }
      s *= 0.125f;
      s += (1.0f - mask[(size_t)b * 2048 + lo + j]) * -1.0e9f;
      ps[wave][j] = s;
      lmax = fmaxf(lmax, s);
    }
#pragma unroll
    for (int off = 32; off; off >>= 1) lmax = fmaxf(lmax, __shfl_xor(lmax, off, 64));

    float lsum = 0.f;
    for (int j = lane; j < nk; j += 64) {
      const float pv = __expf(ps[wave][j] - lmax);
      ps[wave][j] = pv;
      lsum += pv;
    }
#pragma unroll
    for (int off = 32; off; off >>= 1) lsum += __shfl_xor(lsum, off, 64);
    const float inv = 1.0f / lsum;

    // pass 2: out[d] = sum_j p_j * v[lo+j][d]; lane = d
    const float* vbase = v + ((size_t)b * 2048 + lo) * 768 + h * 64 + lane;
    float a0 = 0.f, a1 = 0.f, a2 = 0.f, a3 = 0.f;
    int j = 0;
    for (; j + 4 <= nk; j += 4) {
      a0 += ps[wave][j]     * vbase[(size_t)j * 768];
      a1 += ps[wave][j + 1] * vbase[(size_t)(j + 1) * 768];
      a2 += ps[wave][j + 2] * vbase[(size_t)(j + 2) * 768];
      a3 += ps[wave][j + 3] * vbase[(size_t)(j + 3) * 768];
    }
    for (; j < nk; ++j) a0 += ps[wave][j] * vbase[(size_t)j * 768];
    const float accv = ((a0 + a1) + (a2 + a3)) * inv;
    ab[((size_t)b * 2048 + t) * 768 + h * 64 + lane] = f2bf(accv);
  }
}

// ---------------------------------------------------------------------------
// Embedding gather + LayerNorm. block per token (4096 blocks, 256 thr)
// ---------------------------------------------------------------------------
__global__ __launch_bounds__(256) void embed_ln_kernel(
    const int* __restrict__ ids, const float* __restrict__ wemb, const float* __restrict__ pemb,
    const float* __restrict__ temb, const float* __restrict__ g, const float* __restrict__ be,
    float* __restrict__ x, u16* __restrict__ xb)
{
  const int t = blockIdx.x;
  const int s = t & 2047;
  const int id = ids[t];
  const int tid = threadIdx.x;
  const int wave = tid >> 6, lane = tid & 63;

  float vals[3]; float sum = 0.f, ssq = 0.f;
#pragma unroll
  for (int i = 0; i < 3; ++i) {
    const int d = tid + i * 256;
    const float v = wemb[(size_t)id * 768 + d] + pemb[(size_t)(s + 2) * 768 + d] + temb[d];
    vals[i] = v; sum += v; ssq += v * v;
  }
#pragma unroll
  for (int off = 32; off; off >>= 1) { sum += __shfl_xor(sum, off, 64); ssq += __shfl_xor(ssq, off, 64); }
  __shared__ float rb[8];
  if (lane == 0) { rb[wave] = sum; rb[4 + wave] = ssq; }
  __syncthreads();
  sum = rb[0] + rb[1] + rb[2] + rb[3];
  ssq = rb[4] + rb[5] + rb[6] + rb[7];
  const float mu = sum * (1.f / 768.f);
  const float var = ssq * (1.f / 768.f) - mu * mu;
  const float rstd = rsqrtf(var + 1e-5f);
#pragma unroll
  for (int i = 0; i < 3; ++i) {
    const int d = tid + i * 256;
    const float o = (vals[i] - mu) * rstd * g[d] + be[d];
    x[(size_t)t * 768 + d] = o;
    xb[(size_t)t * 768 + d] = f2bf(o);
  }
}

// ---------------------------------------------------------------------------
// LayerNorm: y f32 -> x f32 + xb bf16. block per token.
// ---------------------------------------------------------------------------
__global__ __launch_bounds__(256) void ln_kernel(
    const float* __restrict__ y, const float* __restrict__ g, const float* __restrict__ be,
    float* __restrict__ x, u16* __restrict__ xb)
{
  const int t = blockIdx.x;
  const int tid = threadIdx.x;
  const int wave = tid >> 6, lane = tid & 63;
  const float* yr = y + (size_t)t * 768;

  float vals[3]; float sum = 0.f, ssq = 0.f;
#pragma unroll
  for (int i = 0; i < 3; ++i) {
    const float v = yr[tid + i * 256];
    vals[i] = v; sum += v; ssq += v * v;
  }
#pragma unroll
  for (int off = 32; off; off >>= 1) { sum += __shfl_xor(sum, off, 64); ssq += __shfl_xor(ssq, off, 64); }
  __shared__ float rb[8];
  if (lane == 0) { rb[wave] = sum; rb[4 + wave] = ssq; }
  __syncthreads();
  sum = rb[0] + rb[1] + rb[2] + rb[3];
  ssq = rb[4] + rb[5] + rb[6] + rb[7];
  const float mu = sum * (1.f / 768.f);
  const float var = ssq * (1.f / 768.f) - mu * mu;
  const float rstd = rsqrtf(var + 1e-5f);
#pragma unroll
  for (int i = 0; i < 3; ++i) {
    const int d = tid + i * 256;
    const float o = (vals[i] - mu) * rstd * g[d] + be[d];
    x[(size_t)t * 768 + d] = o;
    xb[(size_t)t * 768 + d] = f2bf(o);
  }
}

// ---------------------------------------------------------------------------
// Head: out[b] = dot(x[b,0,:], Wtop[0:768]) + fts[b]*Wtop[768] + btop
// ---------------------------------------------------------------------------
__global__ __launch_bounds__(256) void head_kernel(
    const float* __restrict__ x, const float* __restrict__ fts,
    const float* __restrict__ wtop, const float* __restrict__ btop, float* __restrict__ out)
{
  const int tid = threadIdx.x;
  const int wave = tid >> 6, lane = tid & 63;
  __shared__ float rb[4];
  for (int b = 0; b < 2; ++b) {
    float s = 0.f;
    for (int d = tid; d < 768; d += 256)
      s += x[(size_t)b * 2048 * 768 + d] * wtop[d];
#pragma unroll
    for (int off = 32; off; off >>= 1) s += __shfl_xor(s, off, 64);
    if (lane == 0) rb[wave] = s;
    __syncthreads();
    if (tid == 0) {
      float r = rb[0] + rb[1] + rb[2] + rb[3];
      r += fts[b] * wtop[768] + btop[0];
      out[b] = r;
    }
    __syncthreads();
  }
}

// ---------------------------------------------------------------------------
extern "C" void kernel_launch(void* const* d_in, const int* in_sizes, int n_in,
                              void* d_out, int out_size, void* d_ws, size_t ws_size,
                              hipStream_t stream)
{
  const int*   ids  = (const int*)d_in[0];
  const float* mask = (const float*)d_in[1];
  const float* fts  = (const float*)d_in[2];
  const float* wemb = (const float*)d_in[3];
  const float* pemb = (const float*)d_in[4];
  const float* temb = (const float*)d_in[5];
  const float* lneg = (const float*)d_in[6];
  const float* lneb = (const float*)d_in[7];
  const float* Wq   = (const float*)d_in[8];
  const float* bq   = (const float*)d_in[9];
  const float* Wk   = (const float*)d_in[10];
  const float* bk   = (const float*)d_in[11];
  const float* Wv   = (const float*)d_in[12];
  const float* bvv  = (const float*)d_in[13];
  const float* Wo   = (const float*)d_in[14];
  const float* bo   = (const float*)d_in[15];
  const float* ln1g = (const float*)d_in[16];
  const float* ln1b = (const float*)d_in[17];
  const float* W1   = (const float*)d_in[18];
  const float* b1   = (const float*)d_in[19];
  const float* W2   = (const float*)d_in[20];
  const float* b2   = (const float*)d_in[21];
  const float* ln2g = (const float*)d_in[22];
  const float* ln2b = (const float*)d_in[23];
  const float* wtop = (const float*)d_in[24];
  const float* btop = (const float*)d_in[25];

  const size_t SQ = 589824;   // 768*768 elems
  const size_t SF = 2359296;  // 768*3072 elems
  const size_t fixedBytes = 100663296ull; // activations
  const bool batched = ws_size >= fixedBytes + 12ull * (4 * SQ + 2 * SF) * 2 + 65536;
  const size_t nw = batched ? 12 : 1;

  char* p = (char*)d_ws;
  u16* wTq = (u16*)p; p += nw * SQ * 2;
  u16* wTk = (u16*)p; p += nw * SQ * 2;
  u16* wTv = (u16*)p; p += nw * SQ * 2;
  u16* wTo = (u16*)p; p += nw * SQ * 2;
  u16* wT1 = (u16*)p; p += nw * SF * 2;
  u16* wT2 = (u16*)p; p += nw * SF * 2;
  float* x  = (float*)p; p += (size_t)4096 * 768 * 4;
  u16*   xb = (u16*)p;   p += (size_t)4096 * 768 * 2;
  float* y  = (float*)p; p += (size_t)4096 * 768 * 4;
  float* qb = (float*)p; p += (size_t)4096 * 768 * 4;
  float* kb = (float*)p; p += (size_t)4096 * 768 * 4;
  float* vb = (float*)p; p += (size_t)4096 * 768 * 4;
  u16*   ab = (u16*)p;   p += (size_t)4096 * 768 * 2;
  u16*   hb = (u16*)p;   p += (size_t)4096 * 3072 * 2;

  if (batched) {
    transpose_cvt<<<dim3(24, 24, 12), 256, 0, stream>>>(Wq, wTq, 768, 768);
    transpose_cvt<<<dim3(24, 24, 12), 256, 0, stream>>>(Wk, wTk, 768, 768);
    transpose_cvt<<<dim3(24, 24, 12), 256, 0, stream>>>(Wv, wTv, 768, 768);
    transpose_cvt<<<dim3(24, 24, 12), 256, 0, stream>>>(Wo, wTo, 768, 768);
    transpose_cvt<<<dim3(96, 24, 12), 256, 0, stream>>>(W1, wT1, 768, 3072);
    transpose_cvt<<<dim3(24, 96, 12), 256, 0, stream>>>(W2, wT2, 3072, 768);
  }

  embed_ln_kernel<<<4096, 256, 0, stream>>>(ids, wemb, pemb, temb, lneg, lneb, x, xb);

  for (int i = 0; i < 12; ++i) {
    const u16 *WqTl, *WkTl, *WvTl, *WoTl, *W1Tl, *W2Tl;
    if (batched) {
      WqTl = wTq + (size_t)i * SQ; WkTl = wTk + (size_t)i * SQ;
      WvTl = wTv + (size_t)i * SQ; WoTl = wTo + (size_t)i * SQ;
      W1Tl = wT1 + (size_t)i * SF; W2Tl = wT2 + (size_t)i * SF;
    } else {
      transpose_cvt<<<dim3(24, 24, 1), 256, 0, stream>>>(Wq + (size_t)i * SQ, wTq, 768, 768);
      transpose_cvt<<<dim3(24, 24, 1), 256, 0, stream>>>(Wk + (size_t)i * SQ, wTk, 768, 768);
      transpose_cvt<<<dim3(24, 24, 1), 256, 0, stream>>>(Wv + (size_t)i * SQ, wTv, 768, 768);
      transpose_cvt<<<dim3(24, 24, 1), 256, 0, stream>>>(Wo + (size_t)i * SQ, wTo, 768, 768);
      transpose_cvt<<<dim3(96, 24, 1), 256, 0, stream>>>(W1 + (size_t)i * SF, wT1, 768, 3072);
      transpose_cvt<<<dim3(24, 96, 1), 256, 0, stream>>>(W2 + (size_t)i * SF, wT2, 3072, 768);
      WqTl = wTq; WkTl = wTk; WvTl = wTv; WoTl = wTo; W1Tl = wT1; W2Tl = wT2;
    }

    const dim3 g768(6, 32);
    gemm_bt<0><<<g768, 256, 0, stream>>>(xb, WqTl, bq  + (size_t)i * 768, nullptr, qb, nullptr, 4096, 768, 768);
    gemm_bt<0><<<g768, 256, 0, stream>>>(xb, WkTl, bk  + (size_t)i * 768, nullptr, kb, nullptr, 4096, 768, 768);
    gemm_bt<0><<<g768, 256, 0, stream>>>(xb, WvTl, bvv + (size_t)i * 768, nullptr, vb, nullptr, 4096, 768, 768);

    attn_kernel<<<dim3(128, 12, 2), 256, 0, stream>>>(qb, kb, vb, mask, ab, g_halves[i]);

    gemm_bt<1><<<g768, 256, 0, stream>>>(ab, WoTl, bo + (size_t)i * 768, x, y, nullptr, 4096, 768, 768);
    ln_kernel<<<4096, 256, 0, stream>>>(y, ln1g + (size_t)i * 768, ln1b + (size_t)i * 768, x, xb);

    gemm_bt<2><<<dim3(24, 32), 256, 0, stream>>>(xb, W1Tl, b1 + (size_t)i * 3072, nullptr, nullptr, hb, 4096, 3072, 768);
    gemm_bt<1><<<g768, 256, 0, stream>>>(hb, W2Tl, b2 + (size_t)i * 768, x, y, nullptr, 4096, 768, 3072);
    ln_kernel<<<4096, 256, 0, stream>>>(y, ln2g + (size_t)i * 768, ln2b + (size_t)i * 768, x, xb);
  }

  head_kernel<<<1, 256, 0, stream>>>(x, fts, wtop, btop, (float*)d_out);
}

// Round 3
// 3097.849 us; speedup vs baseline: 3.1446x; 3.1446x over previous
//
#include <hip/hip_runtime.h>

typedef unsigned short u16;
using short8  = __attribute__((ext_vector_type(8))) short;
using floatx4 = __attribute__((ext_vector_type(4))) float;

// window one-sided sizes per layer (WINDOWS/2)
static const int g_halves[12] = {16,16,32,32,64,64,128,128,256,256,256,256};

__device__ __forceinline__ float bf2f(u16 u) {
  union { unsigned int i; float f; } x; x.i = ((unsigned int)u) << 16; return x.f;
}
__device__ __forceinline__ u16 f2bf(float f) {
  union { float f; unsigned int i; } x; x.f = f;
  unsigned int r = x.i + 0x7FFFu + ((x.i >> 16) & 1u);
  return (u16)(r >> 16);
}

// async 16B/lane global->LDS; dest is wave-uniform base, lane l lands at base + l*16
__device__ __forceinline__ void gld_lds16(const u16* g, u16* l) {
  __builtin_amdgcn_global_load_lds(
      (const __attribute__((address_space(1))) unsigned int*)g,
      (__attribute__((address_space(3))) unsigned int*)l, 16, 0, 0);
}

// ---------------------------------------------------------------------------
// fused transpose + f32->bf16 convert: in f32 [z][R][C] -> out bf16 [z][C][R]
// separate z-strides so outputs can pack into a fused buffer
// ---------------------------------------------------------------------------
__global__ __launch_bounds__(256) void transpose_cvt(
    const float* __restrict__ in, u16* __restrict__ out, int R, int C,
    size_t inZ, size_t outZ)
{
  __shared__ u16 t[32][33];
  const int tx = threadIdx.x & 31, ty = threadIdx.x >> 5; // 32 x 8
  const size_t bi = (size_t)blockIdx.z * inZ;
  const size_t bo = (size_t)blockIdx.z * outZ;
  const int r0 = blockIdx.y * 32, c0 = blockIdx.x * 32;
#pragma unroll
  for (int j = 0; j < 32; j += 8)
    t[ty + j][tx] = f2bf(in[bi + (size_t)(r0 + ty + j) * C + (c0 + tx)]);
  __syncthreads();
#pragma unroll
  for (int j = 0; j < 32; j += 8)
    out[bo + (size_t)(c0 + ty + j) * R + (r0 + tx)] = t[tx][ty + j];
}

// ---------------------------------------------------------------------------
// GEMM: C[M,N] = A[M,K](bf16) @ B[K,N] given as Bt[N,K](bf16)
// EPI 1: outF = acc+bias+res (f32)
// EPI 2: outB = bf16(gelu_exact(acc+bias))
// EPI 3: QKV fused: N=2304; seg0=Q (scale 0.125, split hi/lo bf16),
//        seg1=K (split hi/lo), seg2=V (bf16); out layout [B,H,S,64]
// ---------------------------------------------------------------------------
template<int EPI>
__global__ __launch_bounds__(256) void gemm_bt(
    const u16* __restrict__ A, const u16* __restrict__ Bt,
    const float* __restrict__ biasA, const float* __restrict__ biasB, const float* __restrict__ biasC,
    const float* __restrict__ res, float* __restrict__ outF, u16* __restrict__ outB,
    u16* __restrict__ qh, u16* __restrict__ ql, u16* __restrict__ kh, u16* __restrict__ kl,
    u16* __restrict__ vv, int M, int N, int K)
{
  __shared__ __align__(16) u16 lsA[128 * 32];
  __shared__ __align__(16) u16 lsB[128 * 32];
  const int tid  = threadIdx.x;
  const int wave = tid >> 6, lane = tid & 63;
  const int quad = lane >> 4, l16 = lane & 15;
  const int m0 = blockIdx.y * 128, n0 = blockIdx.x * 128;
  const int wm = (wave >> 1) * 64, wn = (wave & 1) * 64;
  const int srow = lane >> 2;          // row within 16-row chunk
  const int skof = (lane & 3) * 8;     // bf16 offset along k

  floatx4 acc[4][4] = {};

  for (int k0 = 0; k0 < K; k0 += 32) {
    __syncthreads();
#pragma unroll
    for (int c = wave; c < 16; c += 4) {
      if (c < 8)
        gld_lds16(A  + (size_t)(m0 + c * 16 + srow) * K + k0 + skof, lsA + c * 512);
      else
        gld_lds16(Bt + (size_t)(n0 + (c - 8) * 16 + srow) * K + k0 + skof, lsB + (c - 8) * 512);
    }
    __syncthreads();
    short8 af[4], bfr[4];
#pragma unroll
    for (int i = 0; i < 4; ++i)
      af[i]  = *(const short8*)(lsA + (wm + i * 16 + l16) * 32 + quad * 8);
#pragma unroll
    for (int j = 0; j < 4; ++j)
      bfr[j] = *(const short8*)(lsB + (wn + j * 16 + l16) * 32 + quad * 8);
#pragma unroll
    for (int i = 0; i < 4; ++i)
#pragma unroll
      for (int j = 0; j < 4; ++j)
        acc[i][j] = __builtin_amdgcn_mfma_f32_16x16x32_bf16(af[i], bfr[j], acc[i][j], 0, 0, 0);
  }

#pragma unroll
  for (int i = 0; i < 4; ++i)
#pragma unroll
    for (int j = 0; j < 4; ++j) {
      const int col = n0 + wn + j * 16 + l16;
      if (EPI == 3) {
        const int seg = (col >= 1536) ? 2 : (col >= 768) ? 1 : 0;
        const int cc = col - seg * 768;
        const int hh = cc >> 6, dd = cc & 63;
        const float bvl = (seg == 0) ? biasA[cc] : (seg == 1) ? biasB[cc] : biasC[cc];
#pragma unroll
        for (int r = 0; r < 4; ++r) {
          const int row = m0 + wm + i * 16 + quad * 4 + r;
          const int bI = row >> 11, ss = row & 2047;
          const size_t ob = (((size_t)bI * 12 + hh) * 2048 + ss) * 64 + dd;
          float v = acc[i][j][r] + bvl;
          if (seg == 0) {
            v *= 0.125f;
            const u16 hi = f2bf(v);
            qh[ob] = hi; ql[ob] = f2bf(v - bf2f(hi));
          } else if (seg == 1) {
            const u16 hi = f2bf(v);
            kh[ob] = hi; kl[ob] = f2bf(v - bf2f(hi));
          } else {
            vv[ob] = f2bf(v);
          }
        }
      } else {
        const float bvl = biasA[col];
#pragma unroll
        for (int r = 0; r < 4; ++r) {
          const int row = m0 + wm + i * 16 + quad * 4 + r;
          const size_t idx = (size_t)row * N + col;
          float v = acc[i][j][r] + bvl;
          if (EPI == 1) { v += res[idx]; outF[idx] = v; }
          if (EPI == 2) {
            v = 0.5f * v * (1.0f + erff(v * 0.70710678118654752f));
            outB[idx] = f2bf(v);
          }
        }
      }
    }
}

// ---------------------------------------------------------------------------
// MFMA banded flash attention. grid (S/64, H, B), 256 thr (4 waves x 16 queries).
// qh/ql/kh/kl/v: [B*H, S, 64] bf16 (q pre-scaled by 0.125, q/k split hi+lo).
// mask: [B,S] f32. out ab: [B,S,768] bf16.
// Band per query t: keys in [t-half, t+half] clipped to [0,S).
// ---------------------------------------------------------------------------
__global__ __launch_bounds__(256) void attn_mfma(
    const u16* __restrict__ qh_g, const u16* __restrict__ ql_g,
    const u16* __restrict__ kh_g, const u16* __restrict__ kl_g,
    const u16* __restrict__ v_g,  const float* __restrict__ mask,
    u16* __restrict__ ab, int halfw)
{
  __shared__ __align__(16) u16 lsKh[2048];   // [32 keys][64 d]
  __shared__ __align__(16) u16 lsKl[2048];
  __shared__ __align__(16) u16 lsVT[2560];   // [64 d][32 keys pad 40]
  __shared__ __align__(16) u16 lsP[2560];    // 4 waves x [16 q][32 keys pad 40]

  const int b = blockIdx.z, h = blockIdx.y;
  const int bh = b * 12 + h;
  const int q0 = blockIdx.x * 64;
  const int tid = threadIdx.x, wave = tid >> 6, lane = tid & 63;
  const int quad = lane >> 4, l16 = lane & 15;
  const int qw0 = q0 + wave * 16;

  // Q fragments (A-layout: m=l16, k=quad*8+j), 2 chunks of 32 dims, hi+lo
  const size_t qrow = ((size_t)bh * 2048 + qw0 + l16) * 64 + quad * 8;
  const short8 qhf0 = *(const short8*)(qh_g + qrow);
  const short8 qhf1 = *(const short8*)(qh_g + qrow + 32);
  const short8 qlf0 = *(const short8*)(ql_g + qrow);
  const short8 qlf1 = *(const short8*)(ql_g + qrow + 32);

  floatx4 oacc[4] = {};
  float mrow[4] = {-3.0e38f, -3.0e38f, -3.0e38f, -3.0e38f};
  float lrow[4] = {0.f, 0.f, 0.f, 0.f};

  const int lo_u = (q0 - halfw > 0) ? q0 - halfw : 0;
  const int hi_u = (q0 + 63 + halfw < 2047) ? q0 + 63 + halfw : 2047;
  const int ntiles = (hi_u - lo_u + 32) >> 5;
  const int wlo = qw0 - halfw, whi = qw0 + 15 + halfw;

  u16* Pw = lsP + wave * 640;

  for (int it = 0; it < ntiles; ++it) {
    const int k0 = lo_u + it * 32;
    __syncthreads();
    // stage kh/kl: 8 chunks of 8 keys (1KB each), 2 per wave
#pragma unroll
    for (int s2 = 0; s2 < 2; ++s2) {
      const int c = wave * 2 + s2;
      const u16* src = (c < 4) ? kh_g : kl_g;
      u16* dst = ((c < 4) ? lsKh : lsKl) + (c & 3) * 512;
      const int keyc = k0 + (c & 3) * 8;
      if (keyc + 7 < 2048) {
        gld_lds16(src + ((size_t)bh * 2048 + keyc) * 64 + lane * 8, dst);
      } else {
        const int key = keyc + (lane >> 3);
        if (key < 2048)
          *(short8*)(dst + lane * 8) =
              *(const short8*)(src + ((size_t)bh * 2048 + key) * 64 + (lane & 7) * 8);
      }
    }
    // stage V transposed: VT[d][key]; zero-fill OOB keys (0*NaN poisons MFMA)
    {
      const int key = tid & 31, dg = tid >> 5;
      const int gk2 = k0 + key;
      if (gk2 < 2048) {
        const short8 t8 = *(const short8*)(v_g + ((size_t)bh * 2048 + gk2) * 64 + dg * 8);
#pragma unroll
        for (int e = 0; e < 8; ++e) lsVT[(dg * 8 + e) * 40 + key] = (u16)t8[e];
      } else {
#pragma unroll
        for (int e = 0; e < 8; ++e) lsVT[(dg * 8 + e) * 40 + key] = 0;
      }
    }
    __syncthreads();
    if (k0 + 31 < wlo || k0 > whi) continue;   // outside this wave's band

    // scores: S = Q*K^T via split hi/lo (3 terms), two 16-key C-tiles
    floatx4 sc[2];
#pragma unroll
    for (int ct = 0; ct < 2; ++ct) {
      const u16* kb = lsKh + (ct * 16 + l16) * 64 + quad * 8;
      const u16* lb = lsKl + (ct * 16 + l16) * 64 + quad * 8;
      const short8 kh0 = *(const short8*)(kb);
      const short8 kh1 = *(const short8*)(kb + 32);
      const short8 kl0 = *(const short8*)(lb);
      const short8 kl1 = *(const short8*)(lb + 32);
      floatx4 sa = {};
      sa = __builtin_amdgcn_mfma_f32_16x16x32_bf16(qhf0, kh0, sa, 0, 0, 0);
      sa = __builtin_amdgcn_mfma_f32_16x16x32_bf16(qhf1, kh1, sa, 0, 0, 0);
      sa = __builtin_amdgcn_mfma_f32_16x16x32_bf16(qlf0, kh0, sa, 0, 0, 0);
      sa = __builtin_amdgcn_mfma_f32_16x16x32_bf16(qlf1, kh1, sa, 0, 0, 0);
      sa = __builtin_amdgcn_mfma_f32_16x16x32_bf16(qhf0, kl0, sa, 0, 0, 0);
      sa = __builtin_amdgcn_mfma_f32_16x16x32_bf16(qhf1, kl1, sa, 0, 0, 0);
      sc[ct] = sa;
    }
    // mask add + band mask (select, so K garbage/NaN never propagates)
#pragma unroll
    for (int ct = 0; ct < 2; ++ct) {
      const int g = k0 + ct * 16 + l16;
      const int gc = (g < 2047) ? g : 2047;
      const float ma = (1.0f - mask[b * 2048 + gc]) * -1.0e9f;
#pragma unroll
      for (int r = 0; r < 4; ++r) {
        const int t = qw0 + quad * 4 + r;
        const bool valid = (g >= t - halfw) && (g <= t + halfw) && (g < 2048);
        sc[ct][r] = valid ? sc[ct][r] + ma : -1.0e9f;
      }
    }
    // online softmax per row
    float pr[2][4];
#pragma unroll
    for (int r = 0; r < 4; ++r) {
      float rm = fmaxf(sc[0][r], sc[1][r]);
      rm = fmaxf(rm, __shfl_xor(rm, 1, 64));
      rm = fmaxf(rm, __shfl_xor(rm, 2, 64));
      rm = fmaxf(rm, __shfl_xor(rm, 4, 64));
      rm = fmaxf(rm, __shfl_xor(rm, 8, 64));
      const float mn = fmaxf(mrow[r], rm);
      const float al = __expf(mrow[r] - mn);
      mrow[r] = mn;
      const float p0 = __expf(sc[0][r] - mn);
      const float p1 = __expf(sc[1][r] - mn);
      pr[0][r] = p0; pr[1][r] = p1;
      float rs = p0 + p1;
      rs += __shfl_xor(rs, 1, 64);
      rs += __shfl_xor(rs, 2, 64);
      rs += __shfl_xor(rs, 4, 64);
      rs += __shfl_xor(rs, 8, 64);
      lrow[r] = lrow[r] * al + rs;
#pragma unroll
      for (int dt = 0; dt < 4; ++dt) oacc[dt][r] *= al;
    }
    // P: C-layout -> LDS -> A-layout (per-wave buffer, intra-wave dep only)
#pragma unroll
    for (int ct = 0; ct < 2; ++ct)
#pragma unroll
      for (int r = 0; r < 4; ++r)
        Pw[(quad * 4 + r) * 40 + ct * 16 + l16] = f2bf(pr[ct][r]);
    const short8 pa = *(const short8*)(Pw + l16 * 40 + quad * 8);
#pragma unroll
    for (int dt = 0; dt < 4; ++dt) {
      const short8 vf = *(const short8*)(lsVT + (dt * 16 + l16) * 40 + quad * 8);
      oacc[dt] = __builtin_amdgcn_mfma_f32_16x16x32_bf16(pa, vf, oacc[dt], 0, 0, 0);
    }
  }

  // epilogue: O/l -> ab[B,S,768]
#pragma unroll
  for (int r = 0; r < 4; ++r) {
    const float inv = 1.0f / lrow[r];
    const size_t orow = ((size_t)b * 2048 + qw0 + quad * 4 + r) * 768 + h * 64;
#pragma unroll
    for (int dt = 0; dt < 4; ++dt)
      ab[orow + dt * 16 + l16] = f2bf(oacc[dt][r] * inv);
  }
}

// ---------------------------------------------------------------------------
// Embedding gather + LayerNorm. block per token (4096 blocks, 256 thr)
// ---------------------------------------------------------------------------
__global__ __launch_bounds__(256) void embed_ln_kernel(
    const int* __restrict__ ids, const float* __restrict__ wemb, const float* __restrict__ pemb,
    const float* __restrict__ temb, const float* __restrict__ g, const float* __restrict__ be,
    float* __restrict__ x, u16* __restrict__ xb)
{
  const int t = blockIdx.x;
  const int s = t & 2047;
  const int id = ids[t];
  const int tid = threadIdx.x;
  const int wave = tid >> 6, lane = tid & 63;

  float vals[3]; float sum = 0.f, ssq = 0.f;
#pragma unroll
  for (int i = 0; i < 3; ++i) {
    const int d = tid + i * 256;
    const float v = wemb[(size_t)id * 768 + d] + pemb[(size_t)(s + 2) * 768 + d] + temb[d];
    vals[i] = v; sum += v; ssq += v * v;
  }
#pragma unroll
  for (int off = 32; off; off >>= 1) { sum += __shfl_xor(sum, off, 64); ssq += __shfl_xor(ssq, off, 64); }
  __shared__ float rb[8];
  if (lane == 0) { rb[wave] = sum; rb[4 + wave] = ssq; }
  __syncthreads();
  sum = rb[0] + rb[1] + rb[2] + rb[3];
  ssq = rb[4] + rb[5] + rb[6] + rb[7];
  const float mu = sum * (1.f / 768.f);
  const float var = ssq * (1.f / 768.f) - mu * mu;
  const float rstd = rsqrtf(var + 1e-5f);
#pragma unroll
  for (int i = 0; i < 3; ++i) {
    const int d = tid + i * 256;
    const float o = (vals[i] - mu) * rstd * g[d] + be[d];
    x[(size_t)t * 768 + d] = o;
    xb[(size_t)t * 768 + d] = f2bf(o);
  }
}

// ---------------------------------------------------------------------------
// LayerNorm: y f32 -> x f32 + xb bf16. block per token.
// ---------------------------------------------------------------------------
__global__ __launch_bounds__(256) void ln_kernel(
    const float* __restrict__ y, const float* __restrict__ g, const float* __restrict__ be,
    float* __restrict__ x, u16* __restrict__ xb)
{
  const int t = blockIdx.x;
  const int tid = threadIdx.x;
  const int wave = tid >> 6, lane = tid & 63;
  const float* yr = y + (size_t)t * 768;

  float vals[3]; float sum = 0.f, ssq = 0.f;
#pragma unroll
  for (int i = 0; i < 3; ++i) {
    const float v = yr[tid + i * 256];
    vals[i] = v; sum += v; ssq += v * v;
  }
#pragma unroll
  for (int off = 32; off; off >>= 1) { sum += __shfl_xor(sum, off, 64); ssq += __shfl_xor(ssq, off, 64); }
  __shared__ float rb[8];
  if (lane == 0) { rb[wave] = sum; rb[4 + wave] = ssq; }
  __syncthreads();
  sum = rb[0] + rb[1] + rb[2] + rb[3];
  ssq = rb[4] + rb[5] + rb[6] + rb[7];
  const float mu = sum * (1.f / 768.f);
  const float var = ssq * (1.f / 768.f) - mu * mu;
  const float rstd = rsqrtf(var + 1e-5f);
#pragma unroll
  for (int i = 0; i < 3; ++i) {
    const int d = tid + i * 256;
    const float o = (vals[i] - mu) * rstd * g[d] + be[d];
    x[(size_t)t * 768 + d] = o;
    xb[(size_t)t * 768 + d] = f2bf(o);
  }
}

// ---------------------------------------------------------------------------
// Head: out[b] = dot(x[b,0,:], Wtop[0:768]) + fts[b]*Wtop[768] + btop
// ---------------------------------------------------------------------------
__global__ __launch_bounds__(256) void head_kernel(
    const float* __restrict__ x, const float* __restrict__ fts,
    const float* __restrict__ wtop, const float* __restrict__ btop, float* __restrict__ out)
{
  const int tid = threadIdx.x;
  const int wave = tid >> 6, lane = tid & 63;
  __shared__ float rb[4];
  for (int b = 0; b < 2; ++b) {
    float s = 0.f;
    for (int d = tid; d < 768; d += 256)
      s += x[(size_t)b * 2048 * 768 + d] * wtop[d];
#pragma unroll
    for (int off = 32; off; off >>= 1) s += __shfl_xor(s, off, 64);
    if (lane == 0) rb[wave] = s;
    __syncthreads();
    if (tid == 0) {
      float r = rb[0] + rb[1] + rb[2] + rb[3];
      r += fts[b] * wtop[768] + btop[0];
      out[b] = r;
    }
    __syncthreads();
  }
}

// ---------------------------------------------------------------------------
extern "C" void kernel_launch(void* const* d_in, const int* in_sizes, int n_in,
                              void* d_out, int out_size, void* d_ws, size_t ws_size,
                              hipStream_t stream)
{
  const int*   ids  = (const int*)d_in[0];
  const float* mask = (const float*)d_in[1];
  const float* fts  = (const float*)d_in[2];
  const float* wemb = (const float*)d_in[3];
  const float* pemb = (const float*)d_in[4];
  const float* temb = (const float*)d_in[5];
  const float* lneg = (const float*)d_in[6];
  const float* lneb = (const float*)d_in[7];
  const float* Wq   = (const float*)d_in[8];
  const float* bq   = (const float*)d_in[9];
  const float* Wk   = (const float*)d_in[10];
  const float* bk   = (const float*)d_in[11];
  const float* Wv   = (const float*)d_in[12];
  const float* bvv  = (const float*)d_in[13];
  const float* Wo   = (const float*)d_in[14];
  const float* bo   = (const float*)d_in[15];
  const float* ln1g = (const float*)d_in[16];
  const float* ln1b = (const float*)d_in[17];
  const float* W1   = (const float*)d_in[18];
  const float* b1   = (const float*)d_in[19];
  const float* W2   = (const float*)d_in[20];
  const float* b2   = (const float*)d_in[21];
  const float* ln2g = (const float*)d_in[22];
  const float* ln2b = (const float*)d_in[23];
  const float* wtop = (const float*)d_in[24];
  const float* btop = (const float*)d_in[25];

  const size_t SQ   = 768 * 768;
  const size_t SQ3  = 2304 * 768;
  const size_t SF   = 3072 * 768;
  const size_t perL = SQ3 + SQ + 2 * SF;                 // elems per layer (bf16)
  const size_t NTOK = 4096;
  const size_t HDSZ = (size_t)2 * 12 * 2048 * 64;        // per q/k/v buffer elems

  const size_t fixedBytes =
      NTOK * 768 * 4     // x
    + NTOK * 768 * 2     // xb
    + NTOK * 768 * 4     // y
    + NTOK * 768 * 2     // ab
    + NTOK * 3072 * 2    // hb
    + 5 * HDSZ * 2;      // qh,ql,kh,kl,vb
  const bool batched = ws_size >= fixedBytes + 12 * perL * 2 + 65536;
  const size_t nw = batched ? 12 : 1;

  char* p = (char*)d_ws;
  u16* wTqkv = (u16*)p; p += nw * SQ3 * 2;
  u16* wTo   = (u16*)p; p += nw * SQ  * 2;
  u16* wT1   = (u16*)p; p += nw * SF  * 2;
  u16* wT2   = (u16*)p; p += nw * SF  * 2;
  float* x  = (float*)p; p += NTOK * 768 * 4;
  u16*   xb = (u16*)p;   p += NTOK * 768 * 2;
  float* y  = (float*)p; p += NTOK * 768 * 4;
  u16*   ab = (u16*)p;   p += NTOK * 768 * 2;
  u16*   hb = (u16*)p;   p += NTOK * 3072 * 2;
  u16*   qhB = (u16*)p;  p += HDSZ * 2;
  u16*   qlB = (u16*)p;  p += HDSZ * 2;
  u16*   khB = (u16*)p;  p += HDSZ * 2;
  u16*   klB = (u16*)p;  p += HDSZ * 2;
  u16*   vbB = (u16*)p;  p += HDSZ * 2;

  if (batched) {
    transpose_cvt<<<dim3(24, 24, 12), 256, 0, stream>>>(Wq, wTqkv,             768, 768,  SQ, SQ3);
    transpose_cvt<<<dim3(24, 24, 12), 256, 0, stream>>>(Wk, wTqkv + 768 * 768, 768, 768,  SQ, SQ3);
    transpose_cvt<<<dim3(24, 24, 12), 256, 0, stream>>>(Wv, wTqkv + 1536 * 768,768, 768,  SQ, SQ3);
    transpose_cvt<<<dim3(24, 24, 12), 256, 0, stream>>>(Wo, wTo, 768, 768,  SQ, SQ);
    transpose_cvt<<<dim3(96, 24, 12), 256, 0, stream>>>(W1, wT1, 768, 3072, SF, SF);
    transpose_cvt<<<dim3(24, 96, 12), 256, 0, stream>>>(W2, wT2, 3072, 768, SF, SF);
  }

  embed_ln_kernel<<<4096, 256, 0, stream>>>(ids, wemb, pemb, temb, lneg, lneb, x, xb);

  for (int i = 0; i < 12; ++i) {
    const u16 *WqkvTl, *WoTl, *W1Tl, *W2Tl;
    if (batched) {
      WqkvTl = wTqkv + (size_t)i * SQ3; WoTl = wTo + (size_t)i * SQ;
      W1Tl = wT1 + (size_t)i * SF;      W2Tl = wT2 + (size_t)i * SF;
    } else {
      transpose_cvt<<<dim3(24, 24, 1), 256, 0, stream>>>(Wq + (size_t)i * SQ, wTqkv,             768, 768, SQ, SQ3);
      transpose_cvt<<<dim3(24, 24, 1), 256, 0, stream>>>(Wk + (size_t)i * SQ, wTqkv + 768 * 768, 768, 768, SQ, SQ3);
      transpose_cvt<<<dim3(24, 24, 1), 256, 0, stream>>>(Wv + (size_t)i * SQ, wTqkv + 1536 * 768,768, 768, SQ, SQ3);
      transpose_cvt<<<dim3(24, 24, 1), 256, 0, stream>>>(Wo + (size_t)i * SQ, wTo, 768, 768, SQ, SQ);
      transpose_cvt<<<dim3(96, 24, 1), 256, 0, stream>>>(W1 + (size_t)i * SF, wT1, 768, 3072, SF, SF);
      transpose_cvt<<<dim3(24, 96, 1), 256, 0, stream>>>(W2 + (size_t)i * SF, wT2, 3072, 768, SF, SF);
      WqkvTl = wTqkv; WoTl = wTo; W1Tl = wT1; W2Tl = wT2;
    }

    // fused QKV projection: [4096,768] @ [768,2304]
    gemm_bt<3><<<dim3(18, 32), 256, 0, stream>>>(
        xb, WqkvTl, bq + (size_t)i * 768, bk + (size_t)i * 768, bvv + (size_t)i * 768,
        nullptr, nullptr, nullptr, qhB, qlB, khB, klB, vbB, 4096, 2304, 768);

    attn_mfma<<<dim3(32, 12, 2), 256, 0, stream>>>(qhB, qlB, khB, klB, vbB, mask, ab, g_halves[i]);

    gemm_bt<1><<<dim3(6, 32), 256, 0, stream>>>(
        ab, WoTl, bo + (size_t)i * 768, nullptr, nullptr, x, y, nullptr,
        nullptr, nullptr, nullptr, nullptr, nullptr, 4096, 768, 768);
    ln_kernel<<<4096, 256, 0, stream>>>(y, ln1g + (size_t)i * 768, ln1b + (size_t)i * 768, x, xb);

    gemm_bt<2><<<dim3(24, 32), 256, 0, stream>>>(
        xb, W1Tl, b1 + (size_t)i * 3072, nullptr, nullptr, nullptr, nullptr, hb,
        nullptr, nullptr, nullptr, nullptr, nullptr, 4096, 3072, 768);
    gemm_bt<1><<<dim3(6, 32), 256, 0, stream>>>(
        hb, W2Tl, b2 + (size_t)i * 768, nullptr, nullptr, x, y, nullptr,
        nullptr, nullptr, nullptr, nullptr, nullptr, 4096, 768, 3072);
    ln_kernel<<<4096, 256, 0, stream>>>(y, ln2g + (size_t)i * 768, ln2b + (size_t)i * 768, x, xb);
  }

  head_kernel<<<1, 256, 0, stream>>>(x, fts, wtop, btop, (float*)d_out);
}

// Round 4
// 2656.060 us; speedup vs baseline: 3.6676x; 1.1663x over previous
//
#include <hip/hip_runtime.h>

typedef unsigned short u16;
using short8  = __attribute__((ext_vector_type(8))) short;
using floatx4 = __attribute__((ext_vector_type(4))) float;

// window one-sided sizes per layer (WINDOWS/2)
static const int g_halves[12] = {16,16,32,32,64,64,128,128,256,256,256,256};

__device__ __forceinline__ float bf2f(u16 u) {
  union { unsigned int i; float f; } x; x.i = ((unsigned int)u) << 16; return x.f;
}
__device__ __forceinline__ u16 f2bf(float f) {
  union { float f; unsigned int i; } x; x.f = f;
  unsigned int r = x.i + 0x7FFFu + ((x.i >> 16) & 1u);
  return (u16)(r >> 16);
}

// async 16B/lane global->LDS; dest is wave-uniform base, lane l lands at base + l*16
__device__ __forceinline__ void gld_lds16(const u16* g, u16* l) {
  __builtin_amdgcn_global_load_lds(
      (const __attribute__((address_space(1))) unsigned int*)g,
      (__attribute__((address_space(3))) unsigned int*)l, 16, 0, 0);
}

// ---------------------------------------------------------------------------
// fused transpose + f32->bf16 convert: in f32 [z][R][C] -> out bf16 [z][C][R]
// ---------------------------------------------------------------------------
__global__ __launch_bounds__(256) void transpose_cvt(
    const float* __restrict__ in, u16* __restrict__ out, int R, int C,
    size_t inZ, size_t outZ)
{
  __shared__ u16 t[32][33];
  const int tx = threadIdx.x & 31, ty = threadIdx.x >> 5; // 32 x 8
  const size_t bi = (size_t)blockIdx.z * inZ;
  const size_t bo = (size_t)blockIdx.z * outZ;
  const int r0 = blockIdx.y * 32, c0 = blockIdx.x * 32;
#pragma unroll
  for (int j = 0; j < 32; j += 8)
    t[ty + j][tx] = f2bf(in[bi + (size_t)(r0 + ty + j) * C + (c0 + tx)]);
  __syncthreads();
#pragma unroll
  for (int j = 0; j < 32; j += 8)
    out[bo + (size_t)(c0 + ty + j) * R + (r0 + tx)] = t[tx][ty + j];
}

// ---------------------------------------------------------------------------
// GEMM: C[M,N] = A[M,K](bf16) @ B[K,N] given as Bt[N,K](bf16)
// EPI 2: outB = bf16(gelu_exact(acc+bias))
// EPI 3: QKV fused: N=2304; seg0=Q (scale 0.125, split hi/lo bf16),
//        seg1=K (split hi/lo), seg2=V (bf16); out layout [B,H,S,64]
// EPI 4: split-K partial: outF[(z*M+row)*N+col] = acc (no bias); k in
//        [z*KC, z*KC+KC)
// ---------------------------------------------------------------------------
template<int EPI>
__global__ __launch_bounds__(256) void gemm_bt(
    const u16* __restrict__ A, const u16* __restrict__ Bt,
    const float* __restrict__ biasA, const float* __restrict__ biasB, const float* __restrict__ biasC,
    float* __restrict__ outF, u16* __restrict__ outB,
    u16* __restrict__ qh, u16* __restrict__ ql, u16* __restrict__ kh, u16* __restrict__ kl,
    u16* __restrict__ vv, int M, int N, int K, int KC)
{
  __shared__ __align__(16) u16 lsA[128 * 32];
  __shared__ __align__(16) u16 lsB[128 * 32];
  const int tid  = threadIdx.x;
  const int wave = tid >> 6, lane = tid & 63;
  const int quad = lane >> 4, l16 = lane & 15;
  const int m0 = blockIdx.y * 128, n0 = blockIdx.x * 128;
  const int kz = blockIdx.z * KC;
  const int wm = (wave >> 1) * 64, wn = (wave & 1) * 64;
  const int srow = lane >> 2;          // row within 16-row chunk
  const int skof = (lane & 3) * 8;     // bf16 offset along k

  floatx4 acc[4][4] = {};

  for (int k0 = kz; k0 < kz + KC; k0 += 32) {
    __syncthreads();
#pragma unroll
    for (int c = wave; c < 16; c += 4) {
      if (c < 8)
        gld_lds16(A  + (size_t)(m0 + c * 16 + srow) * K + k0 + skof, lsA + c * 512);
      else
        gld_lds16(Bt + (size_t)(n0 + (c - 8) * 16 + srow) * K + k0 + skof, lsB + (c - 8) * 512);
    }
    __syncthreads();
    short8 af[4], bfr[4];
#pragma unroll
    for (int i = 0; i < 4; ++i)
      af[i]  = *(const short8*)(lsA + (wm + i * 16 + l16) * 32 + quad * 8);
#pragma unroll
    for (int j = 0; j < 4; ++j)
      bfr[j] = *(const short8*)(lsB + (wn + j * 16 + l16) * 32 + quad * 8);
#pragma unroll
    for (int i = 0; i < 4; ++i)
#pragma unroll
      for (int j = 0; j < 4; ++j)
        acc[i][j] = __builtin_amdgcn_mfma_f32_16x16x32_bf16(af[i], bfr[j], acc[i][j], 0, 0, 0);
  }

#pragma unroll
  for (int i = 0; i < 4; ++i)
#pragma unroll
    for (int j = 0; j < 4; ++j) {
      const int col = n0 + wn + j * 16 + l16;
      if (EPI == 3) {
        const int seg = (col >= 1536) ? 2 : (col >= 768) ? 1 : 0;
        const int cc = col - seg * 768;
        const int hh = cc >> 6, dd = cc & 63;
        const float bvl = (seg == 0) ? biasA[cc] : (seg == 1) ? biasB[cc] : biasC[cc];
#pragma unroll
        for (int r = 0; r < 4; ++r) {
          const int row = m0 + wm + i * 16 + quad * 4 + r;
          const int bI = row >> 11, ss = row & 2047;
          const size_t ob = (((size_t)bI * 12 + hh) * 2048 + ss) * 64 + dd;
          float v = acc[i][j][r] + bvl;
          if (seg == 0) {
            v *= 0.125f;
            const u16 hi = f2bf(v);
            qh[ob] = hi; ql[ob] = f2bf(v - bf2f(hi));
          } else if (seg == 1) {
            const u16 hi = f2bf(v);
            kh[ob] = hi; kl[ob] = f2bf(v - bf2f(hi));
          } else {
            vv[ob] = f2bf(v);
          }
        }
      } else if (EPI == 2) {
        const float bvl = biasA[col];
#pragma unroll
        for (int r = 0; r < 4; ++r) {
          const int row = m0 + wm + i * 16 + quad * 4 + r;
          const size_t idx = (size_t)row * N + col;
          float v = acc[i][j][r] + bvl;
          v = 0.5f * v * (1.0f + erff(v * 0.70710678118654752f));
          outB[idx] = f2bf(v);
        }
      } else { // EPI == 4
#pragma unroll
        for (int r = 0; r < 4; ++r) {
          const int row = m0 + wm + i * 16 + quad * 4 + r;
          outF[((size_t)blockIdx.z * M + row) * N + col] = acc[i][j][r];
        }
      }
    }
}

// ---------------------------------------------------------------------------
// MFMA banded flash attention. grid (S/64, H, B), 256 thr (4 waves x 16 queries).
// ---------------------------------------------------------------------------
__global__ __launch_bounds__(256) void attn_mfma(
    const u16* __restrict__ qh_g, const u16* __restrict__ ql_g,
    const u16* __restrict__ kh_g, const u16* __restrict__ kl_g,
    const u16* __restrict__ v_g,  const float* __restrict__ mask,
    u16* __restrict__ ab, int halfw)
{
  __shared__ __align__(16) u16 lsKh[2048];   // [32 keys][64 d]
  __shared__ __align__(16) u16 lsKl[2048];
  __shared__ __align__(16) u16 lsVT[2560];   // [64 d][32 keys pad 40]
  __shared__ __align__(16) u16 lsP[2560];    // 4 waves x [16 q][32 keys pad 40]

  const int b = blockIdx.z, h = blockIdx.y;
  const int bh = b * 12 + h;
  const int q0 = blockIdx.x * 64;
  const int tid = threadIdx.x, wave = tid >> 6, lane = tid & 63;
  const int quad = lane >> 4, l16 = lane & 15;
  const int qw0 = q0 + wave * 16;

  const size_t qrow = ((size_t)bh * 2048 + qw0 + l16) * 64 + quad * 8;
  const short8 qhf0 = *(const short8*)(qh_g + qrow);
  const short8 qhf1 = *(const short8*)(qh_g + qrow + 32);
  const short8 qlf0 = *(const short8*)(ql_g + qrow);
  const short8 qlf1 = *(const short8*)(ql_g + qrow + 32);

  floatx4 oacc[4] = {};
  float mrow[4] = {-3.0e38f, -3.0e38f, -3.0e38f, -3.0e38f};
  float lrow[4] = {0.f, 0.f, 0.f, 0.f};

  const int lo_u = (q0 - halfw > 0) ? q0 - halfw : 0;
  const int hi_u = (q0 + 63 + halfw < 2047) ? q0 + 63 + halfw : 2047;
  const int ntiles = (hi_u - lo_u + 32) >> 5;
  const int wlo = qw0 - halfw, whi = qw0 + 15 + halfw;

  u16* Pw = lsP + wave * 640;

  for (int it = 0; it < ntiles; ++it) {
    const int k0 = lo_u + it * 32;
    __syncthreads();
#pragma unroll
    for (int s2 = 0; s2 < 2; ++s2) {
      const int c = wave * 2 + s2;
      const u16* src = (c < 4) ? kh_g : kl_g;
      u16* dst = ((c < 4) ? lsKh : lsKl) + (c & 3) * 512;
      const int keyc = k0 + (c & 3) * 8;
      if (keyc + 7 < 2048) {
        gld_lds16(src + ((size_t)bh * 2048 + keyc) * 64 + lane * 8, dst);
      } else {
        const int key = keyc + (lane >> 3);
        if (key < 2048)
          *(short8*)(dst + lane * 8) =
              *(const short8*)(src + ((size_t)bh * 2048 + key) * 64 + (lane & 7) * 8);
      }
    }
    {
      const int key = tid & 31, dg = tid >> 5;
      const int gk2 = k0 + key;
      if (gk2 < 2048) {
        const short8 t8 = *(const short8*)(v_g + ((size_t)bh * 2048 + gk2) * 64 + dg * 8);
#pragma unroll
        for (int e = 0; e < 8; ++e) lsVT[(dg * 8 + e) * 40 + key] = (u16)t8[e];
      } else {
#pragma unroll
        for (int e = 0; e < 8; ++e) lsVT[(dg * 8 + e) * 40 + key] = 0;
      }
    }
    __syncthreads();
    if (k0 + 31 < wlo || k0 > whi) continue;

    floatx4 sc[2];
#pragma unroll
    for (int ct = 0; ct < 2; ++ct) {
      const u16* kb = lsKh + (ct * 16 + l16) * 64 + quad * 8;
      const u16* lb = lsKl + (ct * 16 + l16) * 64 + quad * 8;
      const short8 kh0 = *(const short8*)(kb);
      const short8 kh1 = *(const short8*)(kb + 32);
      const short8 kl0 = *(const short8*)(lb);
      const short8 kl1 = *(const short8*)(lb + 32);
      floatx4 sa = {};
      sa = __builtin_amdgcn_mfma_f32_16x16x32_bf16(qhf0, kh0, sa, 0, 0, 0);
      sa = __builtin_amdgcn_mfma_f32_16x16x32_bf16(qhf1, kh1, sa, 0, 0, 0);
      sa = __builtin_amdgcn_mfma_f32_16x16x32_bf16(qlf0, kh0, sa, 0, 0, 0);
      sa = __builtin_amdgcn_mfma_f32_16x16x32_bf16(qlf1, kh1, sa, 0, 0, 0);
      sa = __builtin_amdgcn_mfma_f32_16x16x32_bf16(qhf0, kl0, sa, 0, 0, 0);
      sa = __builtin_amdgcn_mfma_f32_16x16x32_bf16(qhf1, kl1, sa, 0, 0, 0);
      sc[ct] = sa;
    }
#pragma unroll
    for (int ct = 0; ct < 2; ++ct) {
      const int g = k0 + ct * 16 + l16;
      const int gc = (g < 2047) ? g : 2047;
      const float ma = (1.0f - mask[b * 2048 + gc]) * -1.0e9f;
#pragma unroll
      for (int r = 0; r < 4; ++r) {
        const int t = qw0 + quad * 4 + r;
        const bool valid = (g >= t - halfw) && (g <= t + halfw) && (g < 2048);
        sc[ct][r] = valid ? sc[ct][r] + ma : -1.0e9f;
      }
    }
    float pr[2][4];
#pragma unroll
    for (int r = 0; r < 4; ++r) {
      float rm = fmaxf(sc[0][r], sc[1][r]);
      rm = fmaxf(rm, __shfl_xor(rm, 1, 64));
      rm = fmaxf(rm, __shfl_xor(rm, 2, 64));
      rm = fmaxf(rm, __shfl_xor(rm, 4, 64));
      rm = fmaxf(rm, __shfl_xor(rm, 8, 64));
      const float mn = fmaxf(mrow[r], rm);
      const float al = __expf(mrow[r] - mn);
      mrow[r] = mn;
      const float p0 = __expf(sc[0][r] - mn);
      const float p1 = __expf(sc[1][r] - mn);
      pr[0][r] = p0; pr[1][r] = p1;
      float rs = p0 + p1;
      rs += __shfl_xor(rs, 1, 64);
      rs += __shfl_xor(rs, 2, 64);
      rs += __shfl_xor(rs, 4, 64);
      rs += __shfl_xor(rs, 8, 64);
      lrow[r] = lrow[r] * al + rs;
#pragma unroll
      for (int dt = 0; dt < 4; ++dt) oacc[dt][r] *= al;
    }
#pragma unroll
    for (int ct = 0; ct < 2; ++ct)
#pragma unroll
      for (int r = 0; r < 4; ++r)
        Pw[(quad * 4 + r) * 40 + ct * 16 + l16] = f2bf(pr[ct][r]);
    const short8 pa = *(const short8*)(Pw + l16 * 40 + quad * 8);
#pragma unroll
    for (int dt = 0; dt < 4; ++dt) {
      const short8 vf = *(const short8*)(lsVT + (dt * 16 + l16) * 40 + quad * 8);
      oacc[dt] = __builtin_amdgcn_mfma_f32_16x16x32_bf16(pa, vf, oacc[dt], 0, 0, 0);
    }
  }

#pragma unroll
  for (int r = 0; r < 4; ++r) {
    const float inv = 1.0f / lrow[r];
    const size_t orow = ((size_t)b * 2048 + qw0 + quad * 4 + r) * 768 + h * 64;
#pragma unroll
    for (int dt = 0; dt < 4; ++dt)
      ab[orow + dt * 16 + l16] = f2bf(oacc[dt][r] * inv);
  }
}

// ---------------------------------------------------------------------------
// Embedding gather + LayerNorm. block per token (4096 blocks, 256 thr)
// ---------------------------------------------------------------------------
__global__ __launch_bounds__(256) void embed_ln_kernel(
    const int* __restrict__ ids, const float* __restrict__ wemb, const float* __restrict__ pemb,
    const float* __restrict__ temb, const float* __restrict__ g, const float* __restrict__ be,
    float* __restrict__ x, u16* __restrict__ xb)
{
  const int t = blockIdx.x;
  const int s = t & 2047;
  const int id = ids[t];
  const int tid = threadIdx.x;
  const int wave = tid >> 6, lane = tid & 63;

  float vals[3]; float sum = 0.f, ssq = 0.f;
#pragma unroll
  for (int i = 0; i < 3; ++i) {
    const int d = tid + i * 256;
    const float v = wemb[(size_t)id * 768 + d] + pemb[(size_t)(s + 2) * 768 + d] + temb[d];
    vals[i] = v; sum += v; ssq += v * v;
  }
#pragma unroll
  for (int off = 32; off; off >>= 1) { sum += __shfl_xor(sum, off, 64); ssq += __shfl_xor(ssq, off, 64); }
  __shared__ float rb[8];
  if (lane == 0) { rb[wave] = sum; rb[4 + wave] = ssq; }
  __syncthreads();
  sum = rb[0] + rb[1] + rb[2] + rb[3];
  ssq = rb[4] + rb[5] + rb[6] + rb[7];
  const float mu = sum * (1.f / 768.f);
  const float var = ssq * (1.f / 768.f) - mu * mu;
  const float rstd = rsqrtf(var + 1e-5f);
#pragma unroll
  for (int i = 0; i < 3; ++i) {
    const int d = tid + i * 256;
    const float o = (vals[i] - mu) * rstd * g[d] + be[d];
    x[(size_t)t * 768 + d] = o;
    xb[(size_t)t * 768 + d] = f2bf(o);
  }
}

// ---------------------------------------------------------------------------
// Split-K reduce + bias + residual + LayerNorm. block per token.
// y_t = sum_c pb[c][t] + bias + x[t]; x = LN(y)*g+b, xb = bf16(x)
// ---------------------------------------------------------------------------
template<int NC>
__global__ __launch_bounds__(256) void reduce_ln_kernel(
    const float* __restrict__ pb, const float* __restrict__ bias,
    const float* __restrict__ g, const float* __restrict__ be,
    float* x, u16* __restrict__ xb)
{
  const int t = blockIdx.x;
  const int tid = threadIdx.x;
  const int wave = tid >> 6, lane = tid & 63;

  float vals[3]; float sum = 0.f, ssq = 0.f;
#pragma unroll
  for (int i = 0; i < 3; ++i) {
    const int d = tid + i * 256;
    float v = x[(size_t)t * 768 + d] + bias[d];
#pragma unroll
    for (int c = 0; c < NC; ++c)
      v += pb[((size_t)c * 4096 + t) * 768 + d];
    vals[i] = v; sum += v; ssq += v * v;
  }
#pragma unroll
  for (int off = 32; off; off >>= 1) { sum += __shfl_xor(sum, off, 64); ssq += __shfl_xor(ssq, off, 64); }
  __shared__ float rb[8];
  if (lane == 0) { rb[wave] = sum; rb[4 + wave] = ssq; }
  __syncthreads();
  sum = rb[0] + rb[1] + rb[2] + rb[3];
  ssq = rb[4] + rb[5] + rb[6] + rb[7];
  const float mu = sum * (1.f / 768.f);
  const float var = ssq * (1.f / 768.f) - mu * mu;
  const float rstd = rsqrtf(var + 1e-5f);
#pragma unroll
  for (int i = 0; i < 3; ++i) {
    const int d = tid + i * 256;
    const float o = (vals[i] - mu) * rstd * g[d] + be[d];
    x[(size_t)t * 768 + d] = o;
    xb[(size_t)t * 768 + d] = f2bf(o);
  }
}

// ---------------------------------------------------------------------------
// Head: out[b] = dot(x[b,0,:], Wtop[0:768]) + fts[b]*Wtop[768] + btop
// ---------------------------------------------------------------------------
__global__ __launch_bounds__(256) void head_kernel(
    const float* __restrict__ x, const float* __restrict__ fts,
    const float* __restrict__ wtop, const float* __restrict__ btop, float* __restrict__ out)
{
  const int tid = threadIdx.x;
  const int wave = tid >> 6, lane = tid & 63;
  __shared__ float rb[4];
  for (int b = 0; b < 2; ++b) {
    float s = 0.f;
    for (int d = tid; d < 768; d += 256)
      s += x[(size_t)b * 2048 * 768 + d] * wtop[d];
#pragma unroll
    for (int off = 32; off; off >>= 1) s += __shfl_xor(s, off, 64);
    if (lane == 0) rb[wave] = s;
    __syncthreads();
    if (tid == 0) {
      float r = rb[0] + rb[1] + rb[2] + rb[3];
      r += fts[b] * wtop[768] + btop[0];
      out[b] = r;
    }
    __syncthreads();
  }
}

// ---------------------------------------------------------------------------
extern "C" void kernel_launch(void* const* d_in, const int* in_sizes, int n_in,
                              void* d_out, int out_size, void* d_ws, size_t ws_size,
                              hipStream_t stream)
{
  const int*   ids  = (const int*)d_in[0];
  const float* mask = (const float*)d_in[1];
  const float* fts  = (const float*)d_in[2];
  const float* wemb = (const float*)d_in[3];
  const float* pemb = (const float*)d_in[4];
  const float* temb = (const float*)d_in[5];
  const float* lneg = (const float*)d_in[6];
  const float* lneb = (const float*)d_in[7];
  const float* Wq   = (const float*)d_in[8];
  const float* bq   = (const float*)d_in[9];
  const float* Wk   = (const float*)d_in[10];
  const float* bk   = (const float*)d_in[11];
  const float* Wv   = (const float*)d_in[12];
  const float* bvv  = (const float*)d_in[13];
  const float* Wo   = (const float*)d_in[14];
  const float* bo   = (const float*)d_in[15];
  const float* ln1g = (const float*)d_in[16];
  const float* ln1b = (const float*)d_in[17];
  const float* W1   = (const float*)d_in[18];
  const float* b1   = (const float*)d_in[19];
  const float* W2   = (const float*)d_in[20];
  const float* b2   = (const float*)d_in[21];
  const float* ln2g = (const float*)d_in[22];
  const float* ln2b = (const float*)d_in[23];
  const float* wtop = (const float*)d_in[24];
  const float* btop = (const float*)d_in[25];

  const size_t SQ   = 768 * 768;
  const size_t SQ3  = 2304 * 768;
  const size_t SF   = 3072 * 768;
  const size_t perL = SQ3 + SQ + 2 * SF;
  const size_t NTOK = 4096;
  const size_t HDSZ = (size_t)2 * 12 * 2048 * 64;

  const size_t fixedBytes =
      NTOK * 768 * 4          // x
    + NTOK * 768 * 2          // xb
    + 4 * NTOK * 768 * 4      // pb (split-K partials, up to 4 chunks)
    + NTOK * 768 * 2          // ab
    + NTOK * 3072 * 2         // hb
    + 5 * HDSZ * 2;           // qh,ql,kh,kl,vb
  const bool batched = ws_size >= fixedBytes + 12 * perL * 2 + 65536;
  const size_t nw = batched ? 12 : 1;

  char* p = (char*)d_ws;
  u16* wTqkv = (u16*)p; p += nw * SQ3 * 2;
  u16* wTo   = (u16*)p; p += nw * SQ  * 2;
  u16* wT1   = (u16*)p; p += nw * SF  * 2;
  u16* wT2   = (u16*)p; p += nw * SF  * 2;
  float* x  = (float*)p; p += NTOK * 768 * 4;
  u16*   xb = (u16*)p;   p += NTOK * 768 * 2;
  float* pb = (float*)p; p += 4 * NTOK * 768 * 4;
  u16*   ab = (u16*)p;   p += NTOK * 768 * 2;
  u16*   hb = (u16*)p;   p += NTOK * 3072 * 2;
  u16*   qhB = (u16*)p;  p += HDSZ * 2;
  u16*   qlB = (u16*)p;  p += HDSZ * 2;
  u16*   khB = (u16*)p;  p += HDSZ * 2;
  u16*   klB = (u16*)p;  p += HDSZ * 2;
  u16*   vbB = (u16*)p;  p += HDSZ * 2;

  if (batched) {
    transpose_cvt<<<dim3(24, 24, 12), 256, 0, stream>>>(Wq, wTqkv,             768, 768,  SQ, SQ3);
    transpose_cvt<<<dim3(24, 24, 12), 256, 0, stream>>>(Wk, wTqkv + 768 * 768, 768, 768,  SQ, SQ3);
    transpose_cvt<<<dim3(24, 24, 12), 256, 0, stream>>>(Wv, wTqkv + 1536 * 768,768, 768,  SQ, SQ3);
    transpose_cvt<<<dim3(24, 24, 12), 256, 0, stream>>>(Wo, wTo, 768, 768,  SQ, SQ);
    transpose_cvt<<<dim3(96, 24, 12), 256, 0, stream>>>(W1, wT1, 768, 3072, SF, SF);
    transpose_cvt<<<dim3(24, 96, 12), 256, 0, stream>>>(W2, wT2, 3072, 768, SF, SF);
  }

  embed_ln_kernel<<<4096, 256, 0, stream>>>(ids, wemb, pemb, temb, lneg, lneb, x, xb);

  for (int i = 0; i < 12; ++i) {
    const u16 *WqkvTl, *WoTl, *W1Tl, *W2Tl;
    if (batched) {
      WqkvTl = wTqkv + (size_t)i * SQ3; WoTl = wTo + (size_t)i * SQ;
      W1Tl = wT1 + (size_t)i * SF;      W2Tl = wT2 + (size_t)i * SF;
    } else {
      transpose_cvt<<<dim3(24, 24, 1), 256, 0, stream>>>(Wq + (size_t)i * SQ, wTqkv,             768, 768, SQ, SQ3);
      transpose_cvt<<<dim3(24, 24, 1), 256, 0, stream>>>(Wk + (size_t)i * SQ, wTqkv + 768 * 768, 768, 768, SQ, SQ3);
      transpose_cvt<<<dim3(24, 24, 1), 256, 0, stream>>>(Wv + (size_t)i * SQ, wTqkv + 1536 * 768,768, 768, SQ, SQ3);
      transpose_cvt<<<dim3(24, 24, 1), 256, 0, stream>>>(Wo + (size_t)i * SQ, wTo, 768, 768, SQ, SQ);
      transpose_cvt<<<dim3(96, 24, 1), 256, 0, stream>>>(W1 + (size_t)i * SF, wT1, 768, 3072, SF, SF);
      transpose_cvt<<<dim3(24, 96, 1), 256, 0, stream>>>(W2 + (size_t)i * SF, wT2, 3072, 768, SF, SF);
      WqkvTl = wTqkv; WoTl = wTo; W1Tl = wT1; W2Tl = wT2;
    }

    // fused QKV projection: [4096,768] @ [768,2304]
    gemm_bt<3><<<dim3(18, 32), 256, 0, stream>>>(
        xb, WqkvTl, bq + (size_t)i * 768, bk + (size_t)i * 768, bvv + (size_t)i * 768,
        nullptr, nullptr, qhB, qlB, khB, klB, vbB, 4096, 2304, 768, 768);

    attn_mfma<<<dim3(32, 12, 2), 256, 0, stream>>>(qhB, qlB, khB, klB, vbB, mask, ab, g_halves[i]);

    // out-proj: split-K=2 -> partials, then reduce+residual+LN
    gemm_bt<4><<<dim3(6, 32, 2), 256, 0, stream>>>(
        ab, WoTl, nullptr, nullptr, nullptr, pb, nullptr,
        nullptr, nullptr, nullptr, nullptr, nullptr, 4096, 768, 768, 384);
    reduce_ln_kernel<2><<<4096, 256, 0, stream>>>(
        pb, bo + (size_t)i * 768, ln1g + (size_t)i * 768, ln1b + (size_t)i * 768, x, xb);

    // FFN1: gelu epilogue
    gemm_bt<2><<<dim3(24, 32), 256, 0, stream>>>(
        xb, W1Tl, b1 + (size_t)i * 3072, nullptr, nullptr, nullptr, hb,
        nullptr, nullptr, nullptr, nullptr, nullptr, 4096, 3072, 768, 768);

    // FFN2: split-K=4 -> partials, then reduce+residual+LN
    gemm_bt<4><<<dim3(6, 32, 4), 256, 0, stream>>>(
        hb, W2Tl, nullptr, nullptr, nullptr, pb, nullptr,
        nullptr, nullptr, nullptr, nullptr, nullptr, 4096, 768, 3072, 768);
    reduce_ln_kernel<4><<<4096, 256, 0, stream>>>(
        pb, b2 + (size_t)i * 768, ln2g + (size_t)i * 768, ln2b + (size_t)i * 768, x, xb);
  }

  head_kernel<<<1, 256, 0, stream>>>(x, fts, wtop, btop, (float*)d_out);
}

// Round 5
// 2586.356 us; speedup vs baseline: 3.7665x; 1.0270x over previous
//
#include <hip/hip_runtime.h>

typedef unsigned short u16;
using short8   = __attribute__((ext_vector_type(8))) short;
using floatx4  = __attribute__((ext_vector_type(4))) float;
using ushortx4 = __attribute__((ext_vector_type(4))) unsigned short;

// window one-sided sizes per layer (WINDOWS/2)
static const int g_halves[12] = {16,16,32,32,64,64,128,128,256,256,256,256};

__device__ __forceinline__ float bf2f(u16 u) {
  union { unsigned int i; float f; } x; x.i = ((unsigned int)u) << 16; return x.f;
}
__device__ __forceinline__ u16 f2bf(float f) {
  union { float f; unsigned int i; } x; x.f = f;
  unsigned int r = x.i + 0x7FFFu + ((x.i >> 16) & 1u);
  return (u16)(r >> 16);
}

// async 16B/lane global->LDS; dest is wave-uniform base, lane l lands at base + l*16
__device__ __forceinline__ void gld_lds16(const u16* g, u16* l) {
  __builtin_amdgcn_global_load_lds(
      (const __attribute__((address_space(1))) unsigned int*)g,
      (__attribute__((address_space(3))) unsigned int*)l, 16, 0, 0);
}

// ---------------------------------------------------------------------------
// fused transpose + f32->bf16 convert: in f32 [z][R][C] -> out bf16 [z][C][R]
// ---------------------------------------------------------------------------
__global__ __launch_bounds__(256) void transpose_cvt(
    const float* __restrict__ in, u16* __restrict__ out, int R, int C,
    size_t inZ, size_t outZ)
{
  __shared__ u16 t[32][33];
  const int tx = threadIdx.x & 31, ty = threadIdx.x >> 5; // 32 x 8
  const size_t bi = (size_t)blockIdx.z * inZ;
  const size_t bo = (size_t)blockIdx.z * outZ;
  const int r0 = blockIdx.y * 32, c0 = blockIdx.x * 32;
#pragma unroll
  for (int j = 0; j < 32; j += 8)
    t[ty + j][tx] = f2bf(in[bi + (size_t)(r0 + ty + j) * C + (c0 + tx)]);
  __syncthreads();
#pragma unroll
  for (int j = 0; j < 32; j += 8)
    out[bo + (size_t)(c0 + ty + j) * R + (r0 + tx)] = t[tx][ty + j];
}

// ---------------------------------------------------------------------------
// GEMM: C[M,N] = A[M,K](bf16) @ B[K,N] given as Bt[N,K](bf16)
// EPI 2: outB = bf16(gelu_exact(acc+bias))
// EPI 3: QKV fused: N=2304; seg0=Q*0.125 -> qg [B,H,S,64]; seg1=K -> kg
//        [B,H,S,64]; seg2=V -> vt [B,H,64,S] (transposed, packed 8B stores)
// EPI 4: split-K partial: outF[(z*M+row)*N+col] = acc
// ---------------------------------------------------------------------------
template<int EPI>
__global__ __launch_bounds__(256) void gemm_bt(
    const u16* __restrict__ A, const u16* __restrict__ Bt,
    const float* __restrict__ biasA, const float* __restrict__ biasB, const float* __restrict__ biasC,
    float* __restrict__ outF, u16* __restrict__ outB,
    u16* __restrict__ qg, u16* __restrict__ kg, u16* __restrict__ vt,
    int M, int N, int K, int KC)
{
  __shared__ __align__(16) u16 lsA[128 * 32];
  __shared__ __align__(16) u16 lsB[128 * 32];
  const int tid  = threadIdx.x;
  const int wave = tid >> 6, lane = tid & 63;
  const int quad = lane >> 4, l16 = lane & 15;
  const int m0 = blockIdx.y * 128, n0 = blockIdx.x * 128;
  const int kz = blockIdx.z * KC;
  const int wm = (wave >> 1) * 64, wn = (wave & 1) * 64;
  const int srow = lane >> 2;          // row within 16-row chunk
  const int skof = (lane & 3) * 8;     // bf16 offset along k

  floatx4 acc[4][4] = {};

  for (int k0 = kz; k0 < kz + KC; k0 += 32) {
    __syncthreads();
#pragma unroll
    for (int c = wave; c < 16; c += 4) {
      if (c < 8)
        gld_lds16(A  + (size_t)(m0 + c * 16 + srow) * K + k0 + skof, lsA + c * 512);
      else
        gld_lds16(Bt + (size_t)(n0 + (c - 8) * 16 + srow) * K + k0 + skof, lsB + (c - 8) * 512);
    }
    __syncthreads();
    short8 af[4], bfr[4];
#pragma unroll
    for (int i = 0; i < 4; ++i)
      af[i]  = *(const short8*)(lsA + (wm + i * 16 + l16) * 32 + quad * 8);
#pragma unroll
    for (int j = 0; j < 4; ++j)
      bfr[j] = *(const short8*)(lsB + (wn + j * 16 + l16) * 32 + quad * 8);
#pragma unroll
    for (int i = 0; i < 4; ++i)
#pragma unroll
      for (int j = 0; j < 4; ++j)
        acc[i][j] = __builtin_amdgcn_mfma_f32_16x16x32_bf16(af[i], bfr[j], acc[i][j], 0, 0, 0);
  }

#pragma unroll
  for (int i = 0; i < 4; ++i)
#pragma unroll
    for (int j = 0; j < 4; ++j) {
      const int col = n0 + wn + j * 16 + l16;
      if (EPI == 3) {
        const int seg = (col >= 1536) ? 2 : (col >= 768) ? 1 : 0;
        const int cc = col - seg * 768;
        const int hh = cc >> 6, dd = cc & 63;
        const float bvl = (seg == 0) ? biasA[cc] : (seg == 1) ? biasB[cc] : biasC[cc];
        const int row0 = m0 + wm + i * 16 + quad * 4;
        const int bI = row0 >> 11, ss = row0 & 2047;
        const int bh = bI * 12 + hh;
        if (seg == 2) {
          ushortx4 pk;
#pragma unroll
          for (int r = 0; r < 4; ++r) pk[r] = f2bf(acc[i][j][r] + bvl);
          *(ushortx4*)(vt + ((size_t)bh * 64 + dd) * 2048 + ss) = pk;
        } else {
          u16* dst = (seg == 0) ? qg : kg;
          const float scl = (seg == 0) ? 0.125f : 1.0f;
#pragma unroll
          for (int r = 0; r < 4; ++r)
            dst[((size_t)bh * 2048 + ss + r) * 64 + dd] = f2bf((acc[i][j][r] + bvl) * scl);
        }
      } else if (EPI == 2) {
        const float bvl = biasA[col];
#pragma unroll
        for (int r = 0; r < 4; ++r) {
          const int row = m0 + wm + i * 16 + quad * 4 + r;
          const size_t idx = (size_t)row * N + col;
          float v = acc[i][j][r] + bvl;
          v = 0.5f * v * (1.0f + erff(v * 0.70710678118654752f));
          outB[idx] = f2bf(v);
        }
      } else { // EPI == 4
#pragma unroll
        for (int r = 0; r < 4; ++r) {
          const int row = m0 + wm + i * 16 + quad * 4 + r;
          outF[((size_t)blockIdx.z * M + row) * N + col] = acc[i][j][r];
        }
      }
    }
}

// ---------------------------------------------------------------------------
// MFMA banded flash attention, barrier-free. grid (S/64, H, B), 256 thr =
// 4 independent waves x 16 queries. K/Q/VT fragments load directly from
// global (coalesced 16B/lane, L2-served); only P round-trips per-wave LDS.
// No running max: scores are O(1), exp(-1e9)=0 handles masking exactly.
// q: [B,H,S,64] bf16 pre-scaled 0.125; k: [B,H,S,64]; vt: [B,H,64,S].
// ---------------------------------------------------------------------------
__global__ __launch_bounds__(256) void attn_mfma(
    const u16* __restrict__ q_g, const u16* __restrict__ k_g,
    const u16* __restrict__ vt_g, const float* __restrict__ mask,
    u16* __restrict__ ab, int halfw)
{
  __shared__ __align__(16) u16 lsP[4][640];   // per wave [16 q][32 keys pad 40]

  const int b = blockIdx.z, h = blockIdx.y;
  const int bh = b * 12 + h;
  const int wave = threadIdx.x >> 6, lane = threadIdx.x & 63;
  const int quad = lane >> 4, l16 = lane & 15;
  const int qw0 = blockIdx.x * 64 + wave * 16;

  const size_t qrow = ((size_t)bh * 2048 + qw0 + l16) * 64 + quad * 8;
  const short8 qf0 = *(const short8*)(q_g + qrow);
  const short8 qf1 = *(const short8*)(q_g + qrow + 32);

  floatx4 oacc[4] = {};
  float lrow[4] = {0.f, 0.f, 0.f, 0.f};
  u16* Pw = lsP[wave];

  const int klo = ((qw0 - halfw > 0) ? (qw0 - halfw) : 0) & ~31;
  const int khi = (qw0 + 15 + halfw < 2047) ? (qw0 + 15 + halfw) : 2047;

  for (int k0 = klo; k0 <= khi; k0 += 32) {
    // scores: 2 MFMA per 16-key tile (dims 0-31, 32-63)
    floatx4 sc[2];
#pragma unroll
    for (int ct = 0; ct < 2; ++ct) {
      const size_t kr = ((size_t)bh * 2048 + k0 + ct * 16 + l16) * 64 + quad * 8;
      const short8 kf0 = *(const short8*)(k_g + kr);
      const short8 kf1 = *(const short8*)(k_g + kr + 32);
      floatx4 sa = {};
      sa = __builtin_amdgcn_mfma_f32_16x16x32_bf16(qf0, kf0, sa, 0, 0, 0);
      sa = __builtin_amdgcn_mfma_f32_16x16x32_bf16(qf1, kf1, sa, 0, 0, 0);
      sc[ct] = sa;
    }
    // band+mask select (garbage K beyond S never escapes the select), exp
    float pr[2][4];
#pragma unroll
    for (int ct = 0; ct < 2; ++ct) {
      const int g = k0 + ct * 16 + l16;
      const int gc = (g < 2047) ? g : 2047;
      const float ma = (1.0f - mask[b * 2048 + gc]) * -1.0e9f;
#pragma unroll
      for (int r = 0; r < 4; ++r) {
        const int t = qw0 + quad * 4 + r;
        const bool valid = (g >= t - halfw) && (g <= t + halfw) && (g < 2048);
        pr[ct][r] = __expf(valid ? sc[ct][r] + ma : -1.0e9f);
      }
    }
#pragma unroll
    for (int r = 0; r < 4; ++r) {
      float rs = pr[0][r] + pr[1][r];
      rs += __shfl_xor(rs, 1, 64);
      rs += __shfl_xor(rs, 2, 64);
      rs += __shfl_xor(rs, 4, 64);
      rs += __shfl_xor(rs, 8, 64);
      lrow[r] += rs;
    }
    // P: C-layout -> per-wave LDS -> A-layout (intra-wave dep only)
#pragma unroll
    for (int ct = 0; ct < 2; ++ct)
#pragma unroll
      for (int r = 0; r < 4; ++r)
        Pw[(quad * 4 + r) * 40 + ct * 16 + l16] = f2bf(pr[ct][r]);
    const short8 pa = *(const short8*)(Pw + l16 * 40 + quad * 8);
    // PV: B-fragments straight from global VT (p=0 kills any OOB garbage)
#pragma unroll
    for (int dt = 0; dt < 4; ++dt) {
      const size_t vr = ((size_t)bh * 64 + dt * 16 + l16) * 2048 + k0 + quad * 8;
      const short8 vf = *(const short8*)(vt_g + vr);
      oacc[dt] = __builtin_amdgcn_mfma_f32_16x16x32_bf16(pa, vf, oacc[dt], 0, 0, 0);
    }
  }

#pragma unroll
  for (int r = 0; r < 4; ++r) {
    const float inv = 1.0f / lrow[r];
    const size_t orow = ((size_t)b * 2048 + qw0 + quad * 4 + r) * 768 + h * 64;
#pragma unroll
    for (int dt = 0; dt < 4; ++dt)
      ab[orow + dt * 16 + l16] = f2bf(oacc[dt][r] * inv);
  }
}

// ---------------------------------------------------------------------------
// Embedding gather + LayerNorm. block per token (4096 blocks, 256 thr)
// ---------------------------------------------------------------------------
__global__ __launch_bounds__(256) void embed_ln_kernel(
    const int* __restrict__ ids, const float* __restrict__ wemb, const float* __restrict__ pemb,
    const float* __restrict__ temb, const float* __restrict__ g, const float* __restrict__ be,
    float* __restrict__ x, u16* __restrict__ xb)
{
  const int t = blockIdx.x;
  const int s = t & 2047;
  const int id = ids[t];
  const int tid = threadIdx.x;
  const int wave = tid >> 6, lane = tid & 63;

  float vals[3]; float sum = 0.f, ssq = 0.f;
#pragma unroll
  for (int i = 0; i < 3; ++i) {
    const int d = tid + i * 256;
    const float v = wemb[(size_t)id * 768 + d] + pemb[(size_t)(s + 2) * 768 + d] + temb[d];
    vals[i] = v; sum += v; ssq += v * v;
  }
#pragma unroll
  for (int off = 32; off; off >>= 1) { sum += __shfl_xor(sum, off, 64); ssq += __shfl_xor(ssq, off, 64); }
  __shared__ float rb[8];
  if (lane == 0) { rb[wave] = sum; rb[4 + wave] = ssq; }
  __syncthreads();
  sum = rb[0] + rb[1] + rb[2] + rb[3];
  ssq = rb[4] + rb[5] + rb[6] + rb[7];
  const float mu = sum * (1.f / 768.f);
  const float var = ssq * (1.f / 768.f) - mu * mu;
  const float rstd = rsqrtf(var + 1e-5f);
#pragma unroll
  for (int i = 0; i < 3; ++i) {
    const int d = tid + i * 256;
    const float o = (vals[i] - mu) * rstd * g[d] + be[d];
    x[(size_t)t * 768 + d] = o;
    xb[(size_t)t * 768 + d] = f2bf(o);
  }
}

// ---------------------------------------------------------------------------
// Split-K reduce + bias + residual + LayerNorm. block per token.
// ---------------------------------------------------------------------------
template<int NC>
__global__ __launch_bounds__(256) void reduce_ln_kernel(
    const float* __restrict__ pb, const float* __restrict__ bias,
    const float* __restrict__ g, const float* __restrict__ be,
    float* x, u16* __restrict__ xb)
{
  const int t = blockIdx.x;
  const int tid = threadIdx.x;
  const int wave = tid >> 6, lane = tid & 63;

  float vals[3]; float sum = 0.f, ssq = 0.f;
#pragma unroll
  for (int i = 0; i < 3; ++i) {
    const int d = tid + i * 256;
    float v = x[(size_t)t * 768 + d] + bias[d];
#pragma unroll
    for (int c = 0; c < NC; ++c)
      v += pb[((size_t)c * 4096 + t) * 768 + d];
    vals[i] = v; sum += v; ssq += v * v;
  }
#pragma unroll
  for (int off = 32; off; off >>= 1) { sum += __shfl_xor(sum, off, 64); ssq += __shfl_xor(ssq, off, 64); }
  __shared__ float rb[8];
  if (lane == 0) { rb[wave] = sum; rb[4 + wave] = ssq; }
  __syncthreads();
  sum = rb[0] + rb[1] + rb[2] + rb[3];
  ssq = rb[4] + rb[5] + rb[6] + rb[7];
  const float mu = sum * (1.f / 768.f);
  const float var = ssq * (1.f / 768.f) - mu * mu;
  const float rstd = rsqrtf(var + 1e-5f);
#pragma unroll
  for (int i = 0; i < 3; ++i) {
    const int d = tid + i * 256;
    const float o = (vals[i] - mu) * rstd * g[d] + be[d];
    x[(size_t)t * 768 + d] = o;
    xb[(size_t)t * 768 + d] = f2bf(o);
  }
}

// ---------------------------------------------------------------------------
// Head: out[b] = dot(x[b,0,:], Wtop[0:768]) + fts[b]*Wtop[768] + btop
// ---------------------------------------------------------------------------
__global__ __launch_bounds__(256) void head_kernel(
    const float* __restrict__ x, const float* __restrict__ fts,
    const float* __restrict__ wtop, const float* __restrict__ btop, float* __restrict__ out)
{
  const int tid = threadIdx.x;
  const int wave = tid >> 6, lane = tid & 63;
  __shared__ float rb[4];
  for (int b = 0; b < 2; ++b) {
    float s = 0.f;
    for (int d = tid; d < 768; d += 256)
      s += x[(size_t)b * 2048 * 768 + d] * wtop[d];
#pragma unroll
    for (int off = 32; off; off >>= 1) s += __shfl_xor(s, off, 64);
    if (lane == 0) rb[wave] = s;
    __syncthreads();
    if (tid == 0) {
      float r = rb[0] + rb[1] + rb[2] + rb[3];
      r += fts[b] * wtop[768] + btop[0];
      out[b] = r;
    }
    __syncthreads();
  }
}

// ---------------------------------------------------------------------------
extern "C" void kernel_launch(void* const* d_in, const int* in_sizes, int n_in,
                              void* d_out, int out_size, void* d_ws, size_t ws_size,
                              hipStream_t stream)
{
  const int*   ids  = (const int*)d_in[0];
  const float* mask = (const float*)d_in[1];
  const float* fts  = (const float*)d_in[2];
  const float* wemb = (const float*)d_in[3];
  const float* pemb = (const float*)d_in[4];
  const float* temb = (const float*)d_in[5];
  const float* lneg = (const float*)d_in[6];
  const float* lneb = (const float*)d_in[7];
  const float* Wq   = (const float*)d_in[8];
  const float* bq   = (const float*)d_in[9];
  const float* Wk   = (const float*)d_in[10];
  const float* bk   = (const float*)d_in[11];
  const float* Wv   = (const float*)d_in[12];
  const float* bvv  = (const float*)d_in[13];
  const float* Wo   = (const float*)d_in[14];
  const float* bo   = (const float*)d_in[15];
  const float* ln1g = (const float*)d_in[16];
  const float* ln1b = (const float*)d_in[17];
  const float* W1   = (const float*)d_in[18];
  const float* b1   = (const float*)d_in[19];
  const float* W2   = (const float*)d_in[20];
  const float* b2   = (const float*)d_in[21];
  const float* ln2g = (const float*)d_in[22];
  const float* ln2b = (const float*)d_in[23];
  const float* wtop = (const float*)d_in[24];
  const float* btop = (const float*)d_in[25];

  const size_t SQ   = 768 * 768;
  const size_t SQ3  = 2304 * 768;
  const size_t SF   = 3072 * 768;
  const size_t perL = SQ3 + SQ + 2 * SF;
  const size_t NTOK = 4096;
  const size_t HDSZ = (size_t)2 * 12 * 2048 * 64;   // per q/k/vt buffer elems
  const size_t PAD  = 4096;                          // band-edge overread pad

  const size_t fixedBytes =
      NTOK * 768 * 4          // x
    + NTOK * 768 * 2          // xb
    + 4 * NTOK * 768 * 4      // pb (split-K partials)
    + NTOK * 768 * 2          // ab
    + NTOK * 3072 * 2         // hb
    + 3 * (HDSZ + PAD) * 2;   // qB,kB,vtB
  const bool batched = ws_size >= fixedBytes + 12 * perL * 2 + 65536;
  const size_t nw = batched ? 12 : 1;

  char* p = (char*)d_ws;
  u16* wTqkv = (u16*)p; p += nw * SQ3 * 2;
  u16* wTo   = (u16*)p; p += nw * SQ  * 2;
  u16* wT1   = (u16*)p; p += nw * SF  * 2;
  u16* wT2   = (u16*)p; p += nw * SF  * 2;
  float* x  = (float*)p; p += NTOK * 768 * 4;
  u16*   xb = (u16*)p;   p += NTOK * 768 * 2;
  float* pb = (float*)p; p += 4 * NTOK * 768 * 4;
  u16*   ab = (u16*)p;   p += NTOK * 768 * 2;
  u16*   hb = (u16*)p;   p += NTOK * 3072 * 2;
  u16*   qB  = (u16*)p;  p += (HDSZ + PAD) * 2;
  u16*   kB  = (u16*)p;  p += (HDSZ + PAD) * 2;
  u16*   vtB = (u16*)p;  p += (HDSZ + PAD) * 2;

  if (batched) {
    transpose_cvt<<<dim3(24, 24, 12), 256, 0, stream>>>(Wq, wTqkv,             768, 768,  SQ, SQ3);
    transpose_cvt<<<dim3(24, 24, 12), 256, 0, stream>>>(Wk, wTqkv + 768 * 768, 768, 768,  SQ, SQ3);
    transpose_cvt<<<dim3(24, 24, 12), 256, 0, stream>>>(Wv, wTqkv + 1536 * 768,768, 768,  SQ, SQ3);
    transpose_cvt<<<dim3(24, 24, 12), 256, 0, stream>>>(Wo, wTo, 768, 768,  SQ, SQ);
    transpose_cvt<<<dim3(96, 24, 12), 256, 0, stream>>>(W1, wT1, 768, 3072, SF, SF);
    transpose_cvt<<<dim3(24, 96, 12), 256, 0, stream>>>(W2, wT2, 3072, 768, SF, SF);
  }

  embed_ln_kernel<<<4096, 256, 0, stream>>>(ids, wemb, pemb, temb, lneg, lneb, x, xb);

  for (int i = 0; i < 12; ++i) {
    const u16 *WqkvTl, *WoTl, *W1Tl, *W2Tl;
    if (batched) {
      WqkvTl = wTqkv + (size_t)i * SQ3; WoTl = wTo + (size_t)i * SQ;
      W1Tl = wT1 + (size_t)i * SF;      W2Tl = wT2 + (size_t)i * SF;
    } else {
      transpose_cvt<<<dim3(24, 24, 1), 256, 0, stream>>>(Wq + (size_t)i * SQ, wTqkv,             768, 768, SQ, SQ3);
      transpose_cvt<<<dim3(24, 24, 1), 256, 0, stream>>>(Wk + (size_t)i * SQ, wTqkv + 768 * 768, 768, 768, SQ, SQ3);
      transpose_cvt<<<dim3(24, 24, 1), 256, 0, stream>>>(Wv + (size_t)i * SQ, wTqkv + 1536 * 768,768, 768, SQ, SQ3);
      transpose_cvt<<<dim3(24, 24, 1), 256, 0, stream>>>(Wo + (size_t)i * SQ, wTo, 768, 768, SQ, SQ);
      transpose_cvt<<<dim3(96, 24, 1), 256, 0, stream>>>(W1 + (size_t)i * SF, wT1, 768, 3072, SF, SF);
      transpose_cvt<<<dim3(24, 96, 1), 256, 0, stream>>>(W2 + (size_t)i * SF, wT2, 3072, 768, SF, SF);
      WqkvTl = wTqkv; WoTl = wTo; W1Tl = wT1; W2Tl = wT2;
    }

    // fused QKV projection: [4096,768] @ [768,2304] -> q,k,[B,H,S,64]; vt [B,H,64,S]
    gemm_bt<3><<<dim3(18, 32), 256, 0, stream>>>(
        xb, WqkvTl, bq + (size_t)i * 768, bk + (size_t)i * 768, bvv + (size_t)i * 768,
        nullptr, nullptr, qB, kB, vtB, 4096, 2304, 768, 768);

    attn_mfma<<<dim3(32, 12, 2), 256, 0, stream>>>(qB, kB, vtB, mask, ab, g_halves[i]);

    // out-proj: split-K=2 -> partials, then reduce+residual+LN
    gemm_bt<4><<<dim3(6, 32, 2), 256, 0, stream>>>(
        ab, WoTl, nullptr, nullptr, nullptr, pb, nullptr,
        nullptr, nullptr, nullptr, 4096, 768, 768, 384);
    reduce_ln_kernel<2><<<4096, 256, 0, stream>>>(
        pb, bo + (size_t)i * 768, ln1g + (size_t)i * 768, ln1b + (size_t)i * 768, x, xb);

    // FFN1: gelu epilogue
    gemm_bt<2><<<dim3(24, 32), 256, 0, stream>>>(
        xb, W1Tl, b1 + (size_t)i * 3072, nullptr, nullptr, nullptr, hb,
        nullptr, nullptr, nullptr, 4096, 3072, 768, 768);

    // FFN2: split-K=4 -> partials, then reduce+residual+LN
    gemm_bt<4><<<dim3(6, 32, 4), 256, 0, stream>>>(
        hb, W2Tl, nullptr, nullptr, nullptr, pb, nullptr,
        nullptr, nullptr, nullptr, 4096, 768, 3072, 768);
    reduce_ln_kernel<4><<<4096, 256, 0, stream>>>(
        pb, b2 + (size_t)i * 768, ln2g + (size_t)i * 768, ln2b + (size_t)i * 768, x, xb);
  }

  head_kernel<<<1, 256, 0, stream>>>(x, fts, wtop, btop, (float*)d_out);
}